// Round 2
// baseline (1874.976 us; speedup 1.0000x reference)
//
#include <hip/hip_runtime.h>

// Billeh column GLIF forward, spike-compacted.
// Per call: build CSR by pre-neuron (hist -> scan -> reorder), then T steps of
// {compacted scatter over spiking neurons only, dense neuron update emitting
// next spike list}. Double-buffered spike counters/lists.

constexpr int RR = 4;

// ---------------- init: state + deg + counters ----------------
__global__ void init_kernel(const float* __restrict__ v0,
                            float* __restrict__ z, float* __restrict__ v,
                            float* __restrict__ r, float* __restrict__ asc,
                            float* __restrict__ psc, float* __restrict__ psc_rise,
                            float* __restrict__ rec_in,
                            int* __restrict__ deg, int* __restrict__ counters, int N) {
    int i = blockIdx.x * blockDim.x + threadIdx.x;
    if (i < RR * N) { psc[i] = 0.f; psc_rise[i] = 0.f; rec_in[i] = 0.f; }
    if (i < 2 * N) asc[i] = 0.f;
    if (i < N) { z[i] = 0.f; v[i] = v0[i]; r[i] = 0.f; deg[i] = 0; }
    if (i == 0) { counters[0] = 0; counters[1] = 0; }
}

__global__ void hist_kernel(const int* __restrict__ pre, int* __restrict__ deg, int E) {
    int e = blockIdx.x * blockDim.x + threadIdx.x;
    if (e < E) atomicAdd(&deg[pre[e]], 1);
}

// Exclusive scan in 1024-element chunks (256 thr x 4); chunk_tot[b] = chunk sum.
__global__ void scan_kernel(const int* __restrict__ in, int* __restrict__ out,
                            int* __restrict__ chunk_tot, int n) {
    __shared__ int s[256];
    int t = threadIdx.x;
    int base = blockIdx.x * 1024;
    int vv[4]; int sum = 0;
#pragma unroll
    for (int j = 0; j < 4; j++) {
        int idx = base + t * 4 + j;
        vv[j] = (idx < n) ? in[idx] : 0;
        sum += vv[j];
    }
    s[t] = sum; __syncthreads();
    for (int off = 1; off < 256; off <<= 1) {
        int x = (t >= off) ? s[t - off] : 0;
        __syncthreads();
        if (t >= off) s[t] += x;
        __syncthreads();
    }
    int excl = s[t] - sum;
#pragma unroll
    for (int j = 0; j < 4; j++) {
        int idx = base + t * 4 + j;
        if (idx < n) out[idx] = excl;
        excl += vv[j];
    }
    if (t == 255) chunk_tot[blockIdx.x] = s[255];
}

__global__ void scan_fixup(int* __restrict__ offs, int* __restrict__ cursor,
                           const int* __restrict__ chunk_excl, int N, int E) {
    int i = blockIdx.x * blockDim.x + threadIdx.x;
    if (i < N) {
        int o = offs[i] + chunk_excl[i >> 10];
        offs[i] = o;
        cursor[i] = o;
    }
    if (i == 0) offs[N] = E;
}

__global__ void reorder_kernel(const int* __restrict__ pre, const int* __restrict__ post,
                               const int* __restrict__ rc, const float* __restrict__ w,
                               int* __restrict__ cursor, int* __restrict__ slot,
                               float* __restrict__ sw, int E) {
    int e = blockIdx.x * blockDim.x + threadIdx.x;
    if (e >= E) return;
    int p = atomicAdd(&cursor[pre[e]], 1);
    slot[p] = post[e] * RR + rc[e];
    sw[p] = w[e];
}

// ---------------- per-step: compacted scatter ----------------
__global__ void scatter_kernel(const int* __restrict__ list, const int* __restrict__ cnt,
                               const int* __restrict__ offs, const int* __restrict__ slot,
                               const float* __restrict__ sw, float* __restrict__ rec_in) {
    int S = cnt[0];
    int g = (blockIdx.x * blockDim.x + threadIdx.x) >> 4;   // 16-lane groups
    int lane = threadIdx.x & 15;
    int ng = (gridDim.x * blockDim.x) >> 4;
    for (int i = g; i < S; i += ng) {
        int n = list[i];
        int b = offs[n], e2 = offs[n + 1];
        for (int j = b + lane; j < e2; j += 16)
            atomicAdd(rec_in + slot[j], sw[j]);
    }
}

// ---------------- per-step: dense neuron update ----------------
__global__ void update_kernel(const float4* __restrict__ x_t,
                              float4* __restrict__ rec_in,
                              float4* __restrict__ psc,
                              float4* __restrict__ psc_rise,
                              float* __restrict__ z,
                              float* __restrict__ v,
                              float* __restrict__ r,
                              float2* __restrict__ asc,
                              const float* __restrict__ v_th,
                              const float* __restrict__ v_reset,
                              const float* __restrict__ t_ref,
                              const float* __restrict__ decay,
                              const float* __restrict__ cur_f,
                              const float* __restrict__ e_l,
                              const float2* __restrict__ asc_amps,
                              const float2* __restrict__ asc_decay,
                              const float* __restrict__ syn_d4,
                              const float* __restrict__ psc_i4,
                              float* __restrict__ out_t,
                              int* __restrict__ spike_list, int* __restrict__ cnt_append,
                              int* __restrict__ cnt_zero, int N) {
    int n = blockIdx.x * blockDim.x + threadIdx.x;
    if (n == 0) *cnt_zero = 0;   // pre-clear the counter update(t+1) will append to
    if (n >= N) return;

    float4 ri = rec_in[n];
    float4 xt = x_t[n];
    float4 pr = psc_rise[n];
    float4 pc = psc[n];
    float sd[RR] = {syn_d4[0], syn_d4[1], syn_d4[2], syn_d4[3]};
    float pi[RR] = {psc_i4[0], psc_i4[1], psc_i4[2], psc_i4[3]};
    float riv[RR] = {ri.x, ri.y, ri.z, ri.w};
    float xtv[RR] = {xt.x, xt.y, xt.z, xt.w};
    float prv[RR] = {pr.x, pr.y, pr.z, pr.w};
    float pcv[RR] = {pc.x, pc.y, pc.z, pc.w};

    float in_cur = 0.f;
    float npr[RR], npc[RR];
#pragma unroll
    for (int j = 0; j < RR; j++) {
        float inp = riv[j] + xtv[j];                 // rec_in + x_t
        npr[j] = prv[j] * sd[j] + inp * pi[j];       // new psc_rise
        npc[j] = pcv[j] * sd[j] + sd[j] * prv[j];    // new psc (OLD psc_rise, DT=1)
        in_cur += npc[j];
    }
    psc_rise[n] = make_float4(npr[0], npr[1], npr[2], npr[3]);
    psc[n]      = make_float4(npc[0], npc[1], npc[2], npc[3]);
    rec_in[n]   = make_float4(0.f, 0.f, 0.f, 0.f);   // re-zero for next scatter

    float zn = z[n];
    float2 a  = asc[n];
    float asum = a.x + a.y;                          // OLD asc sum
    float2 ad = asc_decay[n];
    float2 aa = asc_amps[n];
    asc[n] = make_float2(ad.x * a.x + zn * aa.x, ad.y * a.y + zn * aa.y);

    float vth = v_th[n];
    float ic  = in_cur + asum;
    float vv  = decay[n] * v[n] + cur_f[n] * (ic + e_l[n]) + zn * (v_reset[n] - vth);
    float vsc = (vv - vth) / vth;
    float rn  = r[n];
    float nz  = (vsc > 0.f) ? 1.f : 0.f;
    if (rn > 0.f) nz = 0.f;                          // refractory mask (OLD r)
    float nr  = fmaxf(rn - 1.f + nz * t_ref[n], 0.f);

    v[n] = vv;
    r[n] = nr;
    z[n] = nz;
    out_t[n] = nz;
    if (nz > 0.f) {
        int p = atomicAdd(cnt_append, 1);
        spike_list[p] = n;
    }
}

extern "C" void kernel_launch(void* const* d_in, const int* in_sizes, int n_in,
                              void* d_out, int out_size, void* d_ws, size_t ws_size,
                              hipStream_t stream) {
    const float* w_rec = (const float*)d_in[0];
    const float* x_ext = (const float*)d_in[1];
    const float* v0    = (const float*)d_in[2];
    const float* v_th  = (const float*)d_in[3];
    const float* v_rst = (const float*)d_in[4];
    const float* t_rf  = (const float*)d_in[5];
    const float* decay = (const float*)d_in[6];
    const float* curf  = (const float*)d_in[7];
    const float* e_l   = (const float*)d_in[8];
    const float* aamps = (const float*)d_in[9];
    const float* adec  = (const float*)d_in[10];
    const float* syn_d = (const float*)d_in[11];
    const float* psc_i = (const float*)d_in[12];
    const int*   pre   = (const int*)d_in[13];
    const int*   post  = (const int*)d_in[14];
    const int*   rc    = (const int*)d_in[15];
    float* out = (float*)d_out;

    const int E = in_sizes[0];
    const int N = in_sizes[2];            // B == 1
    const int T = in_sizes[1] / (N * RR);
    const int nchunks = (N + 1023) / 1024;

    // -------- workspace layout --------
    float* wf       = (float*)d_ws;
    float* rec_in   = wf;                         // 4N
    float* psc      = wf + (size_t)4 * N;         // 4N
    float* psc_rise = wf + (size_t)8 * N;         // 4N
    float* z        = wf + (size_t)12 * N;        // N
    float* v        = wf + (size_t)13 * N;        // N
    float* r        = wf + (size_t)14 * N;        // N
    float* asc      = wf + (size_t)15 * N;        // 2N
    float* sw       = wf + (size_t)17 * N;        // E
    int*   wi       = (int*)(wf + (size_t)17 * N + E);
    int* offs       = wi;                         // N+1
    int* cursor     = offs + (N + 1);             // N+1
    int* deg        = cursor + (N + 1);           // N
    int* chunk_tot  = deg + N;                    // <=1024
    int* chunk_excl = chunk_tot + 1024;           // <=1024
    int* dummy      = chunk_excl + 1024;          // 1024
    int* list0      = dummy + 1024;               // N
    int* list1      = list0 + N;                  // N
    int* counters   = list1 + N;                  // 2
    int* slot       = counters + 2;               // E

    // -------- one-time CSR build (inside timed region, every call) --------
    init_kernel<<<(RR * N + 255) / 256, 256, 0, stream>>>(
        v0, z, v, r, asc, psc, psc_rise, rec_in, deg, counters, N);
    hist_kernel<<<(E + 255) / 256, 256, 0, stream>>>(pre, deg, E);
    scan_kernel<<<nchunks, 256, 0, stream>>>(deg, offs, chunk_tot, N);
    scan_kernel<<<1, 256, 0, stream>>>(chunk_tot, chunk_excl, dummy, nchunks);
    scan_fixup<<<(N + 255) / 256, 256, 0, stream>>>(offs, cursor, chunk_excl, N, E);
    reorder_kernel<<<(E + 255) / 256, 256, 0, stream>>>(
        pre, post, rc, w_rec, cursor, slot, sw, E);

    int* lists[2] = {list0, list1};

    for (int t = 0; t < T; t++) {
        if (t > 0) {  // z == 0 at t == 0
            scatter_kernel<<<256, 256, 0, stream>>>(
                lists[(t - 1) & 1], &counters[(t - 1) & 1], offs, slot, sw, rec_in);
        }
        update_kernel<<<(N + 255) / 256, 256, 0, stream>>>(
            (const float4*)(x_ext + (size_t)t * N * RR),
            (float4*)rec_in, (float4*)psc, (float4*)psc_rise,
            z, v, r, (float2*)asc,
            v_th, v_rst, t_rf, decay, curf, e_l,
            (const float2*)aamps, (const float2*)adec,
            syn_d, psc_i, out + (size_t)t * N,
            lists[t & 1], &counters[t & 1], &counters[(t + 1) & 1], N);
    }
}

// Round 3
// 922.011 us; speedup vs baseline: 2.0336x; 2.0336x over previous
//
#include <hip/hip_runtime.h>

// Billeh column GLIF forward, bitmask-gated full scan.
// Per step: scatter (all E synapses, gated by a 12.5KB L1-resident spike
// bitmask, 4 synapses/thread vectorized) + dense neuron update (emits next
// bitmask via __ballot, no atomics).

constexpr int RR = 4;

// ---------------- one-time setup: state init + slot/param packing ----------
__global__ void setup_kernel(const float* __restrict__ v0,
                             float* __restrict__ z, float* __restrict__ v,
                             float* __restrict__ r, float* __restrict__ asc,
                             float* __restrict__ psc, float* __restrict__ psc_rise,
                             float* __restrict__ rec_in,
                             const int* __restrict__ post, const int* __restrict__ rc,
                             int* __restrict__ slot,
                             const float* __restrict__ v_th, const float* __restrict__ v_rst,
                             const float* __restrict__ t_rf, const float* __restrict__ decay,
                             const float* __restrict__ curf, const float* __restrict__ e_l,
                             const float2* __restrict__ aamps, const float2* __restrict__ adec,
                             float4* __restrict__ p0, float4* __restrict__ p1,
                             float2* __restrict__ p2, int E, int N) {
    int i = blockIdx.x * blockDim.x + threadIdx.x;
    if (i < E) slot[i] = post[i] * RR + rc[i];
    if (i < RR * N) { psc[i] = 0.f; psc_rise[i] = 0.f; rec_in[i] = 0.f; }
    if (i < 2 * N) asc[i] = 0.f;
    if (i < N) {
        z[i] = 0.f; v[i] = v0[i]; r[i] = 0.f;
        p0[i] = make_float4(v_th[i], v_rst[i], t_rf[i], decay[i]);
        float2 aa = aamps[i];
        p1[i] = make_float4(curf[i], e_l[i], aa.x, aa.y);
        p2[i] = adec[i];
    }
}

// ---------------- per-step: bitmask-gated scatter ----------------
__global__ void scatter_kernel(const unsigned long long* __restrict__ mask,
                               const int* __restrict__ pre,
                               const int* __restrict__ slot,
                               const float* __restrict__ w,
                               float* __restrict__ rec_in, int E) {
    int i = blockIdx.x * blockDim.x + threadIdx.x;
    int e0 = i * 4;
    if (e0 + 4 <= E) {
        int4 p = *(const int4*)(pre + e0);
        bool b0 = (mask[p.x >> 6] >> (p.x & 63)) & 1ull;
        bool b1 = (mask[p.y >> 6] >> (p.y & 63)) & 1ull;
        bool b2 = (mask[p.z >> 6] >> (p.z & 63)) & 1ull;
        bool b3 = (mask[p.w >> 6] >> (p.w & 63)) & 1ull;
        if (b0 | b1 | b2 | b3) {
            int4 s = *(const int4*)(slot + e0);
            float4 ww = *(const float4*)(w + e0);
            if (b0) atomicAdd(rec_in + s.x, ww.x);
            if (b1) atomicAdd(rec_in + s.y, ww.y);
            if (b2) atomicAdd(rec_in + s.z, ww.z);
            if (b3) atomicAdd(rec_in + s.w, ww.w);
        }
    } else if (e0 < E) {
        for (int e = e0; e < E; e++) {
            int p = pre[e];
            if ((mask[p >> 6] >> (p & 63)) & 1ull)
                atomicAdd(rec_in + slot[e], w[e]);
        }
    }
}

// ---------------- per-step: dense neuron update ----------------
__global__ void update_kernel(const float4* __restrict__ x_t,
                              float4* __restrict__ rec_in,
                              float4* __restrict__ psc,
                              float4* __restrict__ psc_rise,
                              float* __restrict__ z,
                              float* __restrict__ v,
                              float* __restrict__ r,
                              float2* __restrict__ asc,
                              const float4* __restrict__ p0,   // vth, vrst, tref, decay
                              const float4* __restrict__ p1,   // curf, e_l, aa0, aa1
                              const float2* __restrict__ p2,   // ad0, ad1
                              const float* __restrict__ syn_d4,
                              const float* __restrict__ psc_i4,
                              float* __restrict__ out_t,
                              unsigned long long* __restrict__ mask, int N) {
    int n = blockIdx.x * blockDim.x + threadIdx.x;
    if (n >= N) return;

    float4 ri = rec_in[n];
    float4 xt = x_t[n];
    float4 pr = psc_rise[n];
    float4 pc = psc[n];
    float sd[RR] = {syn_d4[0], syn_d4[1], syn_d4[2], syn_d4[3]};
    float pi[RR] = {psc_i4[0], psc_i4[1], psc_i4[2], psc_i4[3]};
    float riv[RR] = {ri.x, ri.y, ri.z, ri.w};
    float xtv[RR] = {xt.x, xt.y, xt.z, xt.w};
    float prv[RR] = {pr.x, pr.y, pr.z, pr.w};
    float pcv[RR] = {pc.x, pc.y, pc.z, pc.w};

    float in_cur = 0.f;
    float npr[RR], npc[RR];
#pragma unroll
    for (int j = 0; j < RR; j++) {
        float inp = riv[j] + xtv[j];                 // rec_in + x_t
        npr[j] = prv[j] * sd[j] + inp * pi[j];       // new psc_rise
        npc[j] = pcv[j] * sd[j] + sd[j] * prv[j];    // new psc (OLD psc_rise, DT=1)
        in_cur += npc[j];
    }
    psc_rise[n] = make_float4(npr[0], npr[1], npr[2], npr[3]);
    psc[n]      = make_float4(npc[0], npc[1], npc[2], npc[3]);
    rec_in[n]   = make_float4(0.f, 0.f, 0.f, 0.f);   // re-zero for next scatter

    float zn = z[n];
    float2 a  = asc[n];
    float asum = a.x + a.y;                          // OLD asc sum
    float4 P0 = p0[n];                               // vth, vrst, tref, decay
    float4 P1 = p1[n];                               // curf, e_l, aa0, aa1
    float2 ad = p2[n];
    asc[n] = make_float2(ad.x * a.x + zn * P1.z, ad.y * a.y + zn * P1.w);

    float vth = P0.x;
    float ic  = in_cur + asum;
    float vv  = P0.w * v[n] + P1.x * (ic + P1.y) + zn * (P0.y - vth);
    float vsc = (vv - vth) / vth;
    float rn  = r[n];
    float nz  = (vsc > 0.f) ? 1.f : 0.f;
    if (rn > 0.f) nz = 0.f;                          // refractory mask (OLD r)
    float nr  = fmaxf(rn - 1.f + nz * P0.z, 0.f);

    v[n] = vv;
    r[n] = nr;
    z[n] = nz;
    out_t[n] = nz;

    // spike bitmask: one ballot + one store per wave, no atomics.
    unsigned long long bal = __ballot(nz > 0.f);
    if ((threadIdx.x & 63) == 0) mask[n >> 6] = bal;
}

extern "C" void kernel_launch(void* const* d_in, const int* in_sizes, int n_in,
                              void* d_out, int out_size, void* d_ws, size_t ws_size,
                              hipStream_t stream) {
    const float* w_rec = (const float*)d_in[0];
    const float* x_ext = (const float*)d_in[1];
    const float* v0    = (const float*)d_in[2];
    const float* v_th  = (const float*)d_in[3];
    const float* v_rst = (const float*)d_in[4];
    const float* t_rf  = (const float*)d_in[5];
    const float* decay = (const float*)d_in[6];
    const float* curf  = (const float*)d_in[7];
    const float* e_l   = (const float*)d_in[8];
    const float* aamps = (const float*)d_in[9];
    const float* adec  = (const float*)d_in[10];
    const float* syn_d = (const float*)d_in[11];
    const float* psc_i = (const float*)d_in[12];
    const int*   pre   = (const int*)d_in[13];
    const int*   post  = (const int*)d_in[14];
    const int*   rc    = (const int*)d_in[15];
    float* out = (float*)d_out;

    const int E = in_sizes[0];
    const int N = in_sizes[2];            // B == 1
    const int T = in_sizes[1] / (N * RR);

    // -------- workspace layout (floats; all offsets 8B-aligned) --------
    float* wf       = (float*)d_ws;
    float* rec_in   = wf;                         // 4N
    float* psc      = wf + (size_t)4 * N;         // 4N
    float* psc_rise = wf + (size_t)8 * N;         // 4N
    float* z        = wf + (size_t)12 * N;        // N
    float* v        = wf + (size_t)13 * N;        // N
    float* r        = wf + (size_t)14 * N;        // N
    float* asc      = wf + (size_t)15 * N;        // 2N
    float* p0       = wf + (size_t)17 * N;        // 4N
    float* p1       = wf + (size_t)21 * N;        // 4N
    float* p2       = wf + (size_t)25 * N;        // 2N
    int*   slot     = (int*)(wf + (size_t)27 * N);            // E
    unsigned long long* mask = (unsigned long long*)(wf + (size_t)27 * N + E);

    const int setup_n = (E > 4 * N) ? E : 4 * N;
    setup_kernel<<<(setup_n + 255) / 256, 256, 0, stream>>>(
        v0, z, v, r, asc, psc, psc_rise, rec_in,
        post, rc, slot, v_th, v_rst, t_rf, decay, curf, e_l,
        (const float2*)aamps, (const float2*)adec,
        (float4*)p0, (float4*)p1, (float2*)p2, E, N);

    const int E4 = (E + 3) / 4;
    for (int t = 0; t < T; t++) {
        if (t > 0) {  // z == 0 at t == 0: nothing to scatter
            scatter_kernel<<<(E4 + 255) / 256, 256, 0, stream>>>(
                mask, pre, slot, w_rec, rec_in, E);
        }
        update_kernel<<<(N + 255) / 256, 256, 0, stream>>>(
            (const float4*)(x_ext + (size_t)t * N * RR),
            (float4*)rec_in, (float4*)psc, (float4*)psc_rise,
            z, v, r, (float2*)asc,
            (const float4*)p0, (const float4*)p1, (const float2*)p2,
            syn_d, psc_i, out + (size_t)t * N, mask, N);
    }
}